// Round 8
// baseline (123.549 us; speedup 1.0000x reference)
//
#include <hip/hip_runtime.h>
#include <hip/hip_bf16.h>

#define B 128
#define N 32
#define DO 128
#define NA 16
#define H 4
#define DK 64
#define DV 64
#define LN_EPS 1e-5f
#define NEG_SLOPE 0.01f

typedef unsigned short u16;
typedef __attribute__((ext_vector_type(8))) short bf16x8;
typedef __attribute__((ext_vector_type(4))) float f32x4;

__device__ __forceinline__ float leaky(float x) {
    return x >= 0.f ? x : NEG_SLOPE * x;
}

__device__ __forceinline__ u16 f2bf(float x) {
    union { float f; unsigned int u; } v; v.f = x;
    unsigned int r = (v.u + 0x7FFF + ((v.u >> 16) & 1)) >> 16;
    return (u16)r;
}

__device__ __forceinline__ float bf2f(u16 x) {
    union { unsigned int u; float f; } v; v.u = ((unsigned int)x) << 16;
    return v.f;
}

// packed f32->bf16 RNE: 1 instr for 2 values.
__device__ __forceinline__ unsigned int cvtpk(float lo, float hi) {
    unsigned int r;
    asm("v_cvt_pk_bf16_f32 %0, %1, %2" : "=v"(r) : "v"(lo), "v"(hi));
    return r;
}

// DPP partial ops on the VALU pipe (vs __shfl_xor -> ds_bpermute on LDS pipe).
template<int CTRL>
__device__ __forceinline__ float dppadd(float x) {
    return x + __int_as_float(__builtin_amdgcn_update_dpp(
        0, __float_as_int(x), CTRL, 0xF, 0xF, true));
}
template<int CTRL>
__device__ __forceinline__ float dppmax(float x) {
    return fmaxf(x, __int_as_float(__builtin_amdgcn_update_dpp(
        0, __float_as_int(x), CTRL, 0xF, 0xF, true)));
}
// row_ror:N ctrl encodings (16-lane rows)
#define ROR1 0x121
#define ROR2 0x122
#define ROR4 0x124
#define ROR8 0x128

// ---------------------------------------------------------------------------
// kP: one-shot weight prep — 20 independent blocks (parallel prelude).
// ---------------------------------------------------------------------------
__global__ __launch_bounds__(256) void kP(
    const float* __restrict__ Wk, const float* __restrict__ Wq,
    const float* __restrict__ Wv, const float* __restrict__ W_se,
    const float* __restrict__ W_sape, const float* __restrict__ ln_g,
    const float* __restrict__ ln_b, const float* __restrict__ W_f1,
    u16* __restrict__ wTb, u16* __restrict__ wseT, u16* __restrict__ wsapeT,
    u16* __restrict__ sapeTail, u16* __restrict__ wTg,
    float* __restrict__ GW, float* __restrict__ BW)
{
    const int blk = blockIdx.x;
    const int t   = threadIdx.x;
    __shared__ float wls[8192];

    if (blk < 12) {
        const int hh = blk / 3, m = blk % 3;
        const float* src = (m == 0 ? Wq : (m == 1 ? Wk : Wv)) + hh * 8192;
        for (int idx = t; idx < 2048; idx += 256)
            ((float4*)wls)[idx] = ((const float4*)src)[idx];
        __syncthreads();
        u16* dst = wTb + (hh * 3 + m) * 8192;
        for (int idx = t; idx < 8192; idx += 256) {
            const int n = idx >> 7, k = idx & 127;
            dst[idx] = f2bf(wls[k * 64 + n]);
        }
    } else if (blk < 16) {
        const int which = (blk - 12) >> 1;      // 0: W_se, 1: W_sape
        const int chunk = blk & 1;
        const float* src = which ? W_sape : W_se;
        u16* dst = which ? wsapeT : wseT;
        const int k0 = chunk * 64;
        for (int idx = t; idx < 2048; idx += 256)
            ((float4*)wls)[idx] = ((const float4*)(src + k0 * 128))[idx];
        __syncthreads();
        for (int idx = t; idx < 8192; idx += 256) {
            const int n = idx >> 6, kk = idx & 63;
            dst[n * 128 + k0 + kk] = f2bf(wls[kk * 128 + n]);
        }
    } else if (blk == 16) {
        for (int idx = t; idx < 2048; idx += 256)
            wls[idx] = W_sape[128 * 128 + idx];
        __syncthreads();
        for (int idx = t; idx < 4096; idx += 256) {
            const int n = idx >> 5, kk = idx & 31;
            sapeTail[n * 32 + kk] = (kk < 16) ? f2bf(wls[kk * 128 + n]) : (u16)0;
        }
    } else if (blk <= 18) {
        const int base = (blk - 17) * 8192;
        for (int idx = t; idx < 8192; idx += 256) {
            const int g  = base + idx;
            const int hh = g >> 12, c = (g >> 6) & 63, ee = g & 63;
            wTg[g] = f2bf(ln_g[hh * 64 + ee] * W_f1[(hh * 64 + ee) * 64 + c]);
        }
    } else {
        {   // GW fp32-exact
            const int hh = t >> 6, c = t & 63;
            float g = 0.f;
            #pragma unroll 4
            for (int ee = 0; ee < 64; ee++)
                g += ln_g[hh * 64 + ee] * W_f1[(hh * 64 + ee) * 64 + c];
            GW[t] = g;
        }
        {   // BW fp32-exact via partials
            const int c = t & 63, qq = t >> 6;
            float bacc = 0.f;
            #pragma unroll 4
            for (int r = 0; r < 64; r++)
                bacc += ln_b[qq * 64 + r] * W_f1[(qq * 64 + r) * 64 + c];
            wls[qq * 64 + c] = bacc;
        }
        __syncthreads();
        if (t < 64) BW[t] = wls[t] + wls[64 + t] + wls[128 + t] + wls[192 + t];
    }
}

// ---------------------------------------------------------------------------
// Kernel B: 1024 threads; kA fused as phase -1.  EXACT R6 form (proven):
//  - w_out + DG global stores deferred past the LAST barrier; sumD in phase D
//  - softmax 16-lane reductions via DPP row_ror (VALU pipe)
//  - serial wave-4/5 sum loops (R7's DPP-partial rewrite failed refcheck;
//    not retried without standalone verification)
// ---------------------------------------------------------------------------
__global__ __launch_bounds__(1024, 8) void kB(
    const float* __restrict__ states, const float* __restrict__ actions,
    const float* __restrict__ policies,
    const float* __restrict__ b_se, const float* __restrict__ b_sape,
    const u16* __restrict__ wTb, const u16* __restrict__ wseT,
    const u16* __restrict__ wsapeT, const u16* __restrict__ sapeTail,
    const u16* __restrict__ wTg,
    float* __restrict__ w_out,
    float* __restrict__ SG, float* __restrict__ DG,
    float* __restrict__ sumS, float* __restrict__ sumS2,
    float* __restrict__ sumD, float* __restrict__ sumD2,
    float* __restrict__ dotSD)
{
    const int bh   = blockIdx.x;
    const int b    = bh >> 2;
    const int h    = bh & 3;
    const int t    = threadIdx.x;
    const int wave = t >> 6;
    const int e    = t & 63;
    const int q16  = e >> 4;
    const int l16  = e & 15;

    __shared__ alignas(16) u16   sST[32 * 136];
    __shared__ alignas(16) u16   actA[32 * 40];
    __shared__ alignas(16) u16   polA[32 * 40];
    __shared__ alignas(16) u16   sSE[32 * 136];
    __shared__ alignas(16) u16   sXA[32 * 136];
    __shared__ alignas(16) u16   sXP[32 * 136];
    __shared__ alignas(16) u16   qb[32 * 72];
    __shared__ alignas(16) u16   kb[32 * 72];
    __shared__ alignas(16) u16   avaT[64 * 40];
    __shared__ alignas(16) u16   diffb[32 * 72];
    __shared__ alignas(16) u16   wb[32 * 40];
    __shared__ alignas(16) float S32[32 * 68];
    __shared__ alignas(16) u16   Sb[32 * 72];

    // deferred-store registers
    float  wo[8];        // waves 0-1: softmax outputs (e0,e1 per v)
    f32x4  dg_a;         // waves 8-15: DG tile

    // ---- prefetch phase -1 B-operands
    const int mtP   = wave >> 3, ntP = wave & 7;
    const int bcolP = ntP * 16 + l16;
    bf16x8 pse[4];
    {
        const u16* bse_p = wseT + bcolP * 128;
        #pragma unroll
        for (int ks = 0; ks < 4; ks++)
            pse[ks] = *(const bf16x8*)&bse_p[ks * 32 + q16 * 8];
    }
    const bf16x8 btP   = *(const bf16x8*)&sapeTail[bcolP * 32 + q16 * 8];
    const float  bse_c = b_se[bcolP];
    const float  bsp_c = b_sape[bcolP];

    // ---- stage: states/actions/policies -> bf16 LDS
    {
        const int r = t >> 5, c4 = (t & 31) * 4;
        const float4 s4 = *(const float4*)&states[(b * 32 + r) * 128 + c4];
        uint2 u;
        u.x = cvtpk(s4.x, s4.y);
        u.y = cvtpk(s4.z, s4.w);
        *(uint2*)&sST[r * 136 + c4] = u;
    }
    if (t < 512) {
        const int r = t >> 4, c = t & 15;
        actA[r * 40 + c]      = f2bf(actions[(b * 32 + r) * 16 + c]);
        actA[r * 40 + 16 + c] = 0;
    } else {
        const int t2 = t - 512, r = t2 >> 4, c = t2 & 15;
        polA[r * 40 + c]      = f2bf(policies[(b * 32 + r) * 16 + c]);
        polA[r * 40 + 16 + c] = 0;
    }

    bf16x8 psp[4];
    {
        const u16* bsp_p = wsapeT + bcolP * 128;
        #pragma unroll
        for (int ks = 0; ks < 4; ks++)
            psp[ks] = *(const bf16x8*)&bsp_p[ks * 32 + q16 * 8];
    }
    __syncthreads();

    // ---- phase -1: se/xa/xp (wave = tile: mt=wave>>3, nt=wave&7)
    f32x4 acc[2];
    bf16x8 pw0[4];
    {
        const int arow = mtP * 16 + l16;
        const int bcol = bcolP;
        f32x4 a_se = {0.f,0.f,0.f,0.f}, a_sp = {0.f,0.f,0.f,0.f};
        f32x4 a_oa = {0.f,0.f,0.f,0.f}, a_op = {0.f,0.f,0.f,0.f};
        #pragma unroll
        for (int ks = 0; ks < 4; ks++) {
            const bf16x8 af = *(const bf16x8*)&sST[arow * 136 + ks * 32 + q16 * 8];
            a_se = __builtin_amdgcn_mfma_f32_16x16x32_bf16(af, pse[ks], a_se, 0, 0, 0);
            a_sp = __builtin_amdgcn_mfma_f32_16x16x32_bf16(af, psp[ks], a_sp, 0, 0, 0);
        }
        a_oa = __builtin_amdgcn_mfma_f32_16x16x32_bf16(
            *(const bf16x8*)&actA[arow * 40 + q16 * 8], btP, a_oa, 0, 0, 0);
        a_op = __builtin_amdgcn_mfma_f32_16x16x32_bf16(
            *(const bf16x8*)&polA[arow * 40 + q16 * 8], btP, a_op, 0, 0, 0);

        // prefetch phase-A tile 0 weights while MFMAs drain
        {
            const int tau0 = wave * 2;
            const int mat0 = tau0 >> 3;
            const int widx0 = (mat0 == 0) ? 0 : (mat0 == 1 ? 1 : 2);
            const int nt0 = tau0 & 3;
            const u16* wsrc0 = wTb + ((h * 3 + widx0) * 64 + nt0 * 16 + l16) * 128;
            #pragma unroll
            for (int ks = 0; ks < 4; ks++)
                pw0[ks] = *(const bf16x8*)&wsrc0[ks * 32 + q16 * 8];
        }

        const int r0 = mtP * 16 + q16 * 4;
        #pragma unroll
        for (int v = 0; v < 4; v += 2) {
            const unsigned int use = cvtpk(leaky(a_se[v]     + bse_c),
                                           leaky(a_se[v + 1] + bse_c));
            const unsigned int uxa = cvtpk(leaky(a_sp[v]     + a_oa[v]     + bsp_c),
                                           leaky(a_sp[v + 1] + a_oa[v + 1] + bsp_c));
            const unsigned int uxp = cvtpk(leaky(a_sp[v]     + a_op[v]     + bsp_c),
                                           leaky(a_sp[v + 1] + a_op[v + 1] + bsp_c));
            sSE[(r0 + v) * 136 + bcol]     = (u16)use;
            sSE[(r0 + v + 1) * 136 + bcol] = (u16)(use >> 16);
            sXA[(r0 + v) * 136 + bcol]     = (u16)uxa;
            sXA[(r0 + v + 1) * 136 + bcol] = (u16)(uxa >> 16);
            sXP[(r0 + v) * 136 + bcol]     = (u16)uxp;
            sXP[(r0 + v + 1) * 136 + bcol] = (u16)(uxp >> 16);
        }
    }
    __syncthreads();

    // ---- phase A: q,k,ava,avp — 2 tiles/wave, K=128
    #pragma unroll
    for (int p = 0; p < 2; p++) {
        const int tau = wave * 2 + p;
        const int mat = tau >> 3;
        const int mt  = (tau >> 2) & 1, nt = tau & 3;
        const u16* X  = (mat <= 1) ? sSE : (mat == 2 ? sXA : sXP);
        const int widx = (mat == 0) ? 0 : (mat == 1 ? 1 : 2);
        const int arow = mt * 16 + l16;
        const u16* wsrc = wTb + ((h * 3 + widx) * 64 + nt * 16 + l16) * 128;
        f32x4 a = {0.f, 0.f, 0.f, 0.f};
        #pragma unroll
        for (int ks = 0; ks < 4; ks++) {
            const bf16x8 af = *(const bf16x8*)&X[arow * 136 + ks * 32 + q16 * 8];
            const bf16x8 bf = (p == 0) ? pw0[ks]
                                       : *(const bf16x8*)&wsrc[ks * 32 + q16 * 8];
            a = __builtin_amdgcn_mfma_f32_16x16x32_bf16(af, bf, a, 0, 0, 0);
        }
        acc[p] = a;
    }
    #pragma unroll
    for (int p = 0; p < 2; p++) {
        const int tau = wave * 2 + p;
        const int mat = tau >> 3;
        const int mt  = (tau >> 2) & 1, nt = tau & 3;
        const int c   = nt * 16 + l16;
        const int r0  = mt * 16 + q16 * 4;
        if (mat == 0) {
            #pragma unroll
            for (int v = 0; v < 4; v += 2) {
                const unsigned int u = cvtpk(acc[p][v], acc[p][v + 1]);
                qb[(r0 + v) * 72 + c]     = (u16)u;
                qb[(r0 + v + 1) * 72 + c] = (u16)(u >> 16);
            }
        } else if (mat == 1) {
            #pragma unroll
            for (int v = 0; v < 4; v += 2) {
                const unsigned int u = cvtpk(acc[p][v], acc[p][v + 1]);
                kb[(r0 + v) * 72 + c]     = (u16)u;
                kb[(r0 + v + 1) * 72 + c] = (u16)(u >> 16);
            }
        } else if (mat == 2) {
            *(unsigned int*)&avaT[c * 40 + r0]     = cvtpk(acc[p][0], acc[p][1]);
            *(unsigned int*)&avaT[c * 40 + r0 + 2] = cvtpk(acc[p][2], acc[p][3]);
        } // mat==3 (avp) held in regs
    }
    __syncthreads();

    // ---- phase B: scores+softmax (waves 0-1, DPP reduce) | diff (waves 12-15)
    bf16x8 pwg[2];
    if (wave >= 8) {
        const int nt = (wave - 8) & 3;
        const u16* wgp = wTg + (h * 64 + nt * 16 + l16) * 64;
        #pragma unroll
        for (int ks = 0; ks < 2; ks++)
            pwg[ks] = *(const bf16x8*)&wgp[ks * 32 + q16 * 8];
    }
    if (wave < 2) {
        const int mt = wave;
        f32x4 s0 = {0.f,0.f,0.f,0.f}, s1 = {0.f,0.f,0.f,0.f};
        #pragma unroll
        for (int ks = 0; ks < 2; ks++) {
            const bf16x8 af = *(const bf16x8*)&qb[(mt * 16 + l16) * 72 + ks * 32 + q16 * 8];
            const bf16x8 b0 = *(const bf16x8*)&kb[l16 * 72 + ks * 32 + q16 * 8];
            const bf16x8 b1 = *(const bf16x8*)&kb[(16 + l16) * 72 + ks * 32 + q16 * 8];
            s0 = __builtin_amdgcn_mfma_f32_16x16x32_bf16(af, b0, s0, 0, 0, 0);
            s1 = __builtin_amdgcn_mfma_f32_16x16x32_bf16(af, b1, s1, 0, 0, 0);
        }
        #pragma unroll
        for (int v = 0; v < 4; v++) {
            float a0 = s0[v] * 0.125f, a1 = s1[v] * 0.125f;
            float mx = fmaxf(a0, a1);
            mx = dppmax<ROR1>(mx); mx = dppmax<ROR2>(mx);
            mx = dppmax<ROR4>(mx); mx = dppmax<ROR8>(mx);
            float e0 = __expf(a0 - mx), e1 = __expf(a1 - mx);
            float sm = e0 + e1;
            sm = dppadd<ROR1>(sm); sm = dppadd<ROR2>(sm);
            sm = dppadd<ROR4>(sm); sm = dppadd<ROR8>(sm);
            const float inv = 1.f / sm;
            e0 *= inv; e1 *= inv;
            const int i = mt * 16 + q16 * 4 + v;
            const unsigned int uw = cvtpk(e0, e1);
            wb[i * 40 + l16]      = (u16)uw;
            wb[i * 40 + 16 + l16] = (u16)(uw >> 16);
            wo[v * 2]     = e0;          // deferred w_out store
            wo[v * 2 + 1] = e1;
        }
    } else if (wave >= 12) {
        #pragma unroll
        for (int p = 0; p < 2; p++) {
            const int tau = wave * 2 + p;
            const int mt  = (tau >> 2) & 1, nt = tau & 3;
            const int c   = nt * 16 + l16;
            const int r0  = mt * 16 + q16 * 4;
            #pragma unroll
            for (int v = 0; v < 4; v += 2) {
                const float av0 = bf2f(avaT[c * 40 + (r0 + v)]);
                const float av1 = bf2f(avaT[c * 40 + (r0 + v + 1)]);
                const unsigned int u = cvtpk(acc[p][v] - av0, acc[p][v + 1] - av1);
                diffb[(r0 + v) * 72 + c]     = (u16)u;
                diffb[(r0 + v + 1) * 72 + c] = (u16)(u >> 16);
            }
        }
    }
    __syncthreads();

    // ---- phase C: S = w@ava (waves 0-7) | DG = diff@Wg (waves 8-15, store
    //      deferred). No global stores before the next barrier.
    if (wave < 8) {
        const int mt = wave >> 2, nt = wave & 3;
        const bf16x8 af = *(const bf16x8*)&wb[(mt * 16 + l16) * 40 + q16 * 8];
        const bf16x8 bf = *(const bf16x8*)&avaT[(nt * 16 + l16) * 40 + q16 * 8];
        f32x4 a = {0.f, 0.f, 0.f, 0.f};
        a = __builtin_amdgcn_mfma_f32_16x16x32_bf16(af, bf, a, 0, 0, 0);
        const int c = nt * 16 + l16, r0 = mt * 16 + q16 * 4;
        #pragma unroll
        for (int v = 0; v < 4; v += 2) {
            S32[(r0 + v) * 68 + c]     = a[v];
            S32[(r0 + v + 1) * 68 + c] = a[v + 1];
            const unsigned int u = cvtpk(a[v], a[v + 1]);
            Sb[(r0 + v) * 72 + c]     = (u16)u;
            Sb[(r0 + v + 1) * 72 + c] = (u16)(u >> 16);
        }
    } else {
        const int w8 = wave - 8;
        const int mt = w8 >> 2;
        f32x4 a = {0.f, 0.f, 0.f, 0.f};
        #pragma unroll
        for (int ks = 0; ks < 2; ks++) {
            const bf16x8 af = *(const bf16x8*)&diffb[(mt * 16 + l16) * 72 + ks * 32 + q16 * 8];
            a = __builtin_amdgcn_mfma_f32_16x16x32_bf16(af, pwg[ks], a, 0, 0, 0);
        }
        dg_a = a;   // deferred store
    }
    __syncthreads();

    // ---- phase D: dotSD (waves 0-3) | SG+DG stores (waves 8-15) |
    //      sumS (wave 4, lanes 0-31) | sumD (wave 5, lanes 0-31)
    if (wave < 4) {
        const int mt = wave >> 1, nt = wave & 1;
        f32x4 a = {0.f, 0.f, 0.f, 0.f};
        #pragma unroll
        for (int ks = 0; ks < 2; ks++) {
            const bf16x8 af = *(const bf16x8*)&Sb[(mt * 16 + l16) * 72 + ks * 32 + q16 * 8];
            const bf16x8 bf = *(const bf16x8*)&diffb[(nt * 16 + l16) * 72 + ks * 32 + q16 * 8];
            a = __builtin_amdgcn_mfma_f32_16x16x32_bf16(af, bf, a, 0, 0, 0);
        }
        const int j = nt * 16 + l16, r0 = mt * 16 + q16 * 4;
        #pragma unroll
        for (int v = 0; v < 4; v++)
            dotSD[(bh * 32 + r0 + v) * 32 + j] = a[v];
    } else if (wave >= 8) {
        const int w8 = wave - 8;
        const int mt = w8 >> 2, nt = w8 & 3;
        f32x4 a = {0.f, 0.f, 0.f, 0.f};
        #pragma unroll
        for (int ks = 0; ks < 2; ks++) {
            const bf16x8 af = *(const bf16x8*)&Sb[(mt * 16 + l16) * 72 + ks * 32 + q16 * 8];
            a = __builtin_amdgcn_mfma_f32_16x16x32_bf16(af, pwg[ks], a, 0, 0, 0);
        }
        const int c = nt * 16 + l16, r0 = mt * 16 + q16 * 4;
        #pragma unroll
        for (int v = 0; v < 4; v++)
            SG[(bh * 32 + r0 + v) * 64 + c] = a[v];
        #pragma unroll
        for (int v = 0; v < 4; v++)
            DG[(bh * 32 + r0 + v) * 64 + c] = dg_a[v];   // deferred from C
    } else if (t >= 256 && t < 288) {
        const int r = t - 256;
        float s1 = 0.f, s2 = 0.f;
        #pragma unroll
        for (int e4 = 0; e4 < 16; e4++) {
            const float4 v4 = *(const float4*)&S32[r * 68 + e4 * 4];
            s1 += v4.x + v4.y + v4.z + v4.w;
            s2 += v4.x * v4.x + v4.y * v4.y + v4.z * v4.z + v4.w * v4.w;
        }
        sumS[bh * 32 + r] = s1; sumS2[bh * 32 + r] = s2;
    } else if (t >= 320 && t < 352) {
        const int r = t - 320;
        float s1 = 0.f, s2 = 0.f;
        #pragma unroll
        for (int e8 = 0; e8 < 8; e8++) {
            const uint4 u = *(const uint4*)&diffb[r * 72 + e8 * 8];
            const unsigned int uu[4] = {u.x, u.y, u.z, u.w};
            #pragma unroll
            for (int q = 0; q < 4; q++) {
                const float fl = __uint_as_float(uu[q] << 16);
                const float fh = __uint_as_float(uu[q] & 0xffff0000u);
                s1 += fl + fh;
                s2 += fl * fl + fh * fh;
            }
        }
        sumD[bh * 32 + r] = s1; sumD2[bh * 32 + r] = s2;
    }

    // ---- deferred w_out stores (waves 0-1; after all barriers)
    if (wave < 2) {
        const int mt = wave;
        #pragma unroll
        for (int v = 0; v < 4; v++) {
            const int i = mt * 16 + q16 * 4 + v;
            w_out[(bh * 32 + i) * 32 + l16]      = wo[v * 2];
            w_out[(bh * 32 + i) * 32 + 16 + l16] = wo[v * 2 + 1];
        }
    }
}

// ---------------------------------------------------------------------------
// Kernel C (512 blocks: b x 4 i-groups; 256 threads; full j-range per block).
// j-merged: SG/GW/BW/W_f2 register preload amortized 2x, half the block
// ramp/tail. pk covers all 32 j (12 KB). Per-element math identical to R6.
// ---------------------------------------------------------------------------
__global__ __launch_bounds__(256) void kC(
    const float* __restrict__ SG, const float* __restrict__ DG,
    const float* __restrict__ sumS, const float* __restrict__ sumS2,
    const float* __restrict__ sumD, const float* __restrict__ sumD2,
    const float* __restrict__ dotSD, const float* __restrict__ w_all,
    const float* __restrict__ GW, const float* __restrict__ BW,
    const float* __restrict__ W_f2, float* __restrict__ value)
{
    const int blk = blockIdx.x;          // b*4 + ig
    const int b   = blk >> 2;
    const int i0  = (blk & 3) * 8;
    const int t   = threadIdx.x;
    const int w0  = t >> 6;              // 0..3
    const int e   = t & 63;

    __shared__ alignas(16) float pk[8 * 32 * 12];   // [ii][j][hh*3 + {a,b,c}]

    // per-(ii,j,hh) LN coefficients: a=inv, b=inv*w, c=-inv*mu
    for (int idx = t; idx < 1024; idx += 256) {
        const int ii = idx >> 7, j = (idx >> 2) & 31, hh = idx & 3;
        const int hi = (b * 4 + hh) * 32 + i0 + ii;
        const int hj = (b * 4 + hh) * 32 + j;
        const float wv  = w_all[hi * 32 + j];
        const float dsd = dotSD[hi * 32 + j];
        const float mu  = (sumS[hi] + wv * sumD[hj]) * (1.f / 64.f);
        const float e2  = (sumS2[hi] + 2.f * wv * dsd + wv * wv * sumD2[hj]) * (1.f / 64.f);
        const float var = fmaxf(e2 - mu * mu, 0.f);
        const float inv = rsqrtf(var + LN_EPS);
        float* rec = &pk[(ii * 32 + j) * 12 + hh * 3];
        rec[0] = inv;
        rec[1] = inv * wv;
        rec[2] = -inv * mu;
    }

    // register-resident row data (independent of pk; loads overlap the sync)
    const float bwr = BW[e];
    const float f2v = W_f2[e];
    float gw[4], sg[8][4];
    #pragma unroll
    for (int hh = 0; hh < 4; hh++) {
        gw[hh] = GW[hh * 64 + e];
        #pragma unroll
        for (int ii = 0; ii < 8; ii++)
            sg[ii][hh] = SG[((b * 4 + hh) * 32 + i0 + ii) * 64 + e];
    }
    __syncthreads();

    for (int jb = 0; jb < 8; jb++) {
        const int j = jb * 4 + w0;       // 0..31, wave-uniform
        float d[4];
        #pragma unroll
        for (int hh = 0; hh < 4; hh++)
            d[hh] = DG[((b * 4 + hh) * 32 + j) * 64 + e];
        #pragma unroll
        for (int ii = 0; ii < 8; ii++) {
            const float* rec = &pk[(ii * 32 + j) * 12];
            const f32x4 r0 = *(const f32x4*)rec;         // a0 b0 c0 a1
            const f32x4 r1 = *(const f32x4*)(rec + 4);   // b1 c1 a2 b2
            const f32x4 r2 = *(const f32x4*)(rec + 8);   // c2 a3 b3 c3
            float z = bwr;
            z += r0[0] * sg[ii][0]; z += r0[1] * d[0]; z += r0[2] * gw[0];
            z += r0[3] * sg[ii][1]; z += r1[0] * d[1]; z += r1[1] * gw[1];
            z += r1[2] * sg[ii][2]; z += r1[3] * d[2]; z += r2[0] * gw[2];
            z += r2[1] * sg[ii][3]; z += r2[2] * d[3]; z += r2[3] * gw[3];
            float p = leaky(z) * f2v;
            p = dppadd<0x111>(p);
            p = dppadd<0x112>(p);
            p = dppadd<0x114>(p);
            p = dppadd<0x118>(p);
            p = dppadd<0x142>(p);
            p = dppadd<0x143>(p);
            if (e == 63) value[(b * 32 + i0 + ii) * 32 + j] = p;
        }
    }
}

extern "C" void kernel_launch(void* const* d_in, const int* in_sizes, int n_in,
                              void* d_out, int out_size, void* d_ws, size_t ws_size,
                              hipStream_t stream)
{
    const float* states   = (const float*)d_in[0];
    const float* policies = (const float*)d_in[1];
    const float* actions  = (const float*)d_in[2];
    const float* W_se     = (const float*)d_in[3];
    const float* b_se     = (const float*)d_in[4];
    const float* W_sape   = (const float*)d_in[5];
    const float* b_sape   = (const float*)d_in[6];
    const float* Wk       = (const float*)d_in[7];
    const float* Wq       = (const float*)d_in[8];
    const float* Wv       = (const float*)d_in[9];
    const float* ln_g     = (const float*)d_in[10];
    const float* ln_b     = (const float*)d_in[11];
    const float* W_f1     = (const float*)d_in[12];
    const float* W_f2     = (const float*)d_in[13];

    float* out_value = (float*)d_out;
    float* out_w     = out_value + B * N * N;

    float* ws    = (float*)d_ws;
    float* SG    = ws;                       // 1,048,576
    float* DG    = SG    + 1048576;          // 1,048,576
    float* sumS  = DG    + 1048576;          // 16,384
    float* sumS2 = sumS  + 16384;
    float* sumD  = sumS2 + 16384;
    float* sumD2 = sumD  + 16384;
    float* dotSD = sumD2 + 16384;            // 524,288
    float* GW    = dotSD + 524288;           // 256
    float* BW    = GW    + 256;              // 64
    u16*   wTb   = (u16*)(BW + 64);          // 98,304
    u16*   wseT  = wTb   + 98304;            // 16,384
    u16*   wsapeT= wseT  + 16384;            // 16,384
    u16*   sapeTail = wsapeT + 16384;        // 4,096
    u16*   wTg   = sapeTail + 4096;          // 16,384

    kP<<<20, 256, 0, stream>>>(Wk, Wq, Wv, W_se, W_sape, ln_g, ln_b, W_f1,
                               wTb, wseT, wsapeT, sapeTail, wTg, GW, BW);
    kB<<<B * H, 1024, 0, stream>>>(states, actions, policies, b_se, b_sape,
                                   wTb, wseT, wsapeT, sapeTail, wTg, out_w,
                                   SG, DG, sumS, sumS2, sumD, sumD2, dotSD);
    kC<<<B * 4, 256, 0, stream>>>(SG, DG, sumS, sumS2, sumD, sumD2, dotSD,
                                  out_w, GW, BW, W_f2, out_value);
}